// Round 2
// baseline (1252.711 us; speedup 1.0000x reference)
//
#include <hip/hip_runtime.h>
#include <hip/hip_bf16.h>

#define B_ 4
#define S_ 2048
#define D_ 1024
#define H_ 16
#define BH_ 64
#define TSZ 8388608L  // B*S*D elements

typedef short short8 __attribute__((ext_vector_type(8)));
typedef float f32x4 __attribute__((ext_vector_type(4)));

__device__ inline unsigned short f2b(float f) {
  __hip_bfloat16 h = __float2bfloat16(f);
  return __builtin_bit_cast(unsigned short, h);
}

// ---------------- GEMM: C[M,N] = A[M,K] @ W[K,N] + bias ---------------------
// MODE 0: out f32, out[row*N + col]
// MODE 1: out bf16, row=(b,s), col=(h,dd) -> out[((b*H+h)*S + s)*64 + dd]
template <bool ABF16, int MODE>
__global__ __launch_bounds__(256) void gemm_kernel(
    const void* __restrict__ Av, const float* __restrict__ W,
    const float* __restrict__ bias, void* __restrict__ outv,
    int M, int N, int K) {
  __shared__ unsigned short Asm[128 * 40];   // [row][k] pitch 40
  __shared__ unsigned short Bsm[128 * 40];   // W^T: [n][k] pitch 40
  const int tid = threadIdx.x;
  const int lane = tid & 63, wid = tid >> 6;
  const int g = lane >> 4, li = lane & 15;
  const int wm = wid >> 1, wn = wid & 1;
  const long bm = (long)blockIdx.x * 128;
  const long bn = (long)blockIdx.y * 128;

  f32x4 acc[4][4];
#pragma unroll
  for (int i = 0; i < 4; i++)
#pragma unroll
    for (int j = 0; j < 4; j++) acc[i][j] = (f32x4){0.f, 0.f, 0.f, 0.f};

  for (int kt = 0; kt < K / 32; ++kt) {
    const int k0 = kt * 32;
    if (ABF16) {
      const unsigned short* A = (const unsigned short*)Av;
#pragma unroll
      for (int p = 0; p < 2; p++) {
        int e = (p * 256 + tid) * 8;
        int r = e >> 5, c = e & 31;
        short8 v = *(const short8*)(A + (bm + r) * K + k0 + c);
        *(short8*)(&Asm[r * 40 + c]) = v;
      }
    } else {
      const float* A = (const float*)Av;
#pragma unroll
      for (int p = 0; p < 4; p++) {
        int e = (p * 256 + tid) * 4;
        int r = e >> 5, c = e & 31;
        float4 v = *(const float4*)(A + (bm + r) * K + k0 + c);
        ushort4 u;
        u.x = f2b(v.x); u.y = f2b(v.y); u.z = f2b(v.z); u.w = f2b(v.w);
        *(ushort4*)(&Asm[r * 40 + c]) = u;
      }
    }
#pragma unroll
    for (int p = 0; p < 4; p++) {
      int e = (p * 256 + tid) * 4;
      int r = e >> 7, c = e & 127;
      float4 v = *(const float4*)(W + (long)(k0 + r) * N + bn + c);
      Bsm[(c + 0) * 40 + r] = f2b(v.x);
      Bsm[(c + 1) * 40 + r] = f2b(v.y);
      Bsm[(c + 2) * 40 + r] = f2b(v.z);
      Bsm[(c + 3) * 40 + r] = f2b(v.w);
    }
    __syncthreads();
    short8 af[4], bf[4];
#pragma unroll
    for (int i = 0; i < 4; i++)
      af[i] = *(const short8*)(&Asm[(wm * 64 + i * 16 + li) * 40 + g * 8]);
#pragma unroll
    for (int i = 0; i < 4; i++)
      bf[i] = *(const short8*)(&Bsm[(wn * 64 + i * 16 + li) * 40 + g * 8]);
#pragma unroll
    for (int i = 0; i < 4; i++)
#pragma unroll
      for (int j = 0; j < 4; j++)
        acc[i][j] =
            __builtin_amdgcn_mfma_f32_16x16x32_bf16(af[i], bf[j], acc[i][j], 0, 0, 0);
    __syncthreads();
  }

#pragma unroll
  for (int i = 0; i < 4; i++) {
    int row0 = (int)bm + wm * 64 + i * 16 + g * 4;
#pragma unroll
    for (int j = 0; j < 4; j++) {
      int col = (int)bn + wn * 64 + j * 16 + li;
      float bvv = bias[col];
#pragma unroll
      for (int jj = 0; jj < 4; jj++) {
        int row = row0 + jj;
        float v = acc[i][j][jj] + bvv;
        if (MODE == 0) {
          ((float*)outv)[(long)row * N + col] = v;
        } else {
          int b = row >> 11, s = row & 2047;
          int h = col >> 6, dd = col & 63;
          ((unsigned short*)outv)[(((long)(b * H_ + h)) * S_ + s) * 64 + dd] = f2b(v);
        }
      }
    }
  }
}

// ---------------- transpose v (BH,S,64) -> vt (BH,64,S) --------------------
__global__ __launch_bounds__(256) void transpose_v(
    const unsigned short* __restrict__ v, unsigned short* __restrict__ vt) {
  __shared__ unsigned short t[64 * 72];
  const int tid = threadIdx.x;
  const int bh = blockIdx.y;
  const int s0 = blockIdx.x * 64;
  const unsigned short* vp = v + ((long)bh * S_ + s0) * 64;
#pragma unroll
  for (int p = 0; p < 2; p++) {
    int e = (p * 256 + tid) * 8;
    int r = e >> 6, c = e & 63;
    short8 x = *(const short8*)(vp + r * 64 + c);
    *(short8*)(&t[r * 72 + c]) = x;
  }
  __syncthreads();
  unsigned short* vo = vt + (long)bh * 64 * S_ + s0;
#pragma unroll
  for (int p = 0; p < 2; p++) {
    int e = (p * 256 + tid) * 8;
    int dd = e >> 6, sc = e & 63;
    short8 x;
#pragma unroll
    for (int i = 0; i < 8; i++) x[i] = (short)t[(sc + i) * 72 + dd];
    *(short8*)(vo + (long)dd * S_ + sc) = x;
  }
}

// ---------------- fused scores/softmax/PV ----------------------------------
__global__ __launch_bounds__(256) void attn_kernel(
    const unsigned short* __restrict__ q,   // (BH,S,64)
    const unsigned short* __restrict__ k,   // (BH,S,64)
    const unsigned short* __restrict__ vt,  // (BH,64,S)
    const int* __restrict__ mask,           // (B,S,S)
    float* __restrict__ attn,               // (BH,S,S) f32
    unsigned short* __restrict__ ctx) {     // (B,S,D) bf16
  __shared__ unsigned short k_lds[128 * 72];       // [key][dd] pitch 72
  __shared__ unsigned short vt_lds[64 * 136];      // [dd][key] pitch 136
  __shared__ unsigned short p_lds[4 * 16 * 136];   // per-wave [qrow][key]
  const int tid = threadIdx.x;
  const int lane = tid & 63, wid = tid >> 6;
  const int g = lane >> 4, li = lane & 15;
  const int bh = blockIdx.y;
  const int b = bh >> 4, h = bh & 15;
  const int qw = blockIdx.x * 64 + wid * 16;

  const unsigned short* qp = q + ((long)bh * S_ + qw) * 64;
  const short8 aq0 = *(const short8*)(qp + li * 64 + g * 8);
  const short8 aq1 = *(const short8*)(qp + li * 64 + 32 + g * 8);
  const int* mrow = mask + (long)b * S_ * S_;

  float lsum[4] = {0.f, 0.f, 0.f, 0.f};
  // ---- pass 1: denominators ----
  for (int kt = 0; kt < 16; ++kt) {
    const unsigned short* kp = k + ((long)bh * S_ + kt * 128) * 64;
#pragma unroll
    for (int p = 0; p < 4; p++) {
      int e = (p * 256 + tid) * 8;
      int r = e >> 6, c = e & 63;
      *(short8*)(&k_lds[r * 72 + c]) = *(const short8*)(kp + r * 64 + c);
    }
    __syncthreads();
#pragma unroll
    for (int nb = 0; nb < 8; nb++) {
      short8 b0 = *(const short8*)(&k_lds[(nb * 16 + li) * 72 + g * 8]);
      short8 b1 = *(const short8*)(&k_lds[(nb * 16 + li) * 72 + 32 + g * 8]);
      f32x4 s = (f32x4){0.f, 0.f, 0.f, 0.f};
      s = __builtin_amdgcn_mfma_f32_16x16x32_bf16(aq0, b0, s, 0, 0, 0);
      s = __builtin_amdgcn_mfma_f32_16x16x32_bf16(aq1, b1, s, 0, 0, 0);
      int key = kt * 128 + nb * 16 + li;
#pragma unroll
      for (int j = 0; j < 4; j++) {
        int qrow = qw + g * 4 + j;
        int mv = mrow[(long)qrow * S_ + key];
        float sc = s[j] * 0.125f + (mv ? 0.f : -1e9f);
        lsum[j] += __expf(sc);
      }
    }
    __syncthreads();
  }
#pragma unroll
  for (int j = 0; j < 4; j++) {
    float v = lsum[j];
    v += __shfl_xor(v, 1);
    v += __shfl_xor(v, 2);
    v += __shfl_xor(v, 4);
    v += __shfl_xor(v, 8);
    lsum[j] = (v > 0.f) ? 1.0f / v : 0.f;  // now reciprocal
  }

  f32x4 c[4];
#pragma unroll
  for (int i = 0; i < 4; i++) c[i] = (f32x4){0.f, 0.f, 0.f, 0.f};
  unsigned short* pbase = &p_lds[wid * 16 * 136];

  // ---- pass 2: probs + PV ----
  for (int kt = 0; kt < 16; ++kt) {
    const unsigned short* kp = k + ((long)bh * S_ + kt * 128) * 64;
#pragma unroll
    for (int p = 0; p < 4; p++) {
      int e = (p * 256 + tid) * 8;
      int r = e >> 6, c2 = e & 63;
      *(short8*)(&k_lds[r * 72 + c2]) = *(const short8*)(kp + r * 64 + c2);
    }
    const unsigned short* vp = vt + (long)bh * 64 * S_ + kt * 128;
#pragma unroll
    for (int p = 0; p < 4; p++) {
      int e = (p * 256 + tid) * 8;
      int r = e >> 7, c2 = e & 127;
      *(short8*)(&vt_lds[r * 136 + c2]) = *(const short8*)(vp + (long)r * S_ + c2);
    }
    __syncthreads();
#pragma unroll
    for (int nb = 0; nb < 8; nb++) {
      short8 b0 = *(const short8*)(&k_lds[(nb * 16 + li) * 72 + g * 8]);
      short8 b1 = *(const short8*)(&k_lds[(nb * 16 + li) * 72 + 32 + g * 8]);
      f32x4 s = (f32x4){0.f, 0.f, 0.f, 0.f};
      s = __builtin_amdgcn_mfma_f32_16x16x32_bf16(aq0, b0, s, 0, 0, 0);
      s = __builtin_amdgcn_mfma_f32_16x16x32_bf16(aq1, b1, s, 0, 0, 0);
      int key = kt * 128 + nb * 16 + li;
#pragma unroll
      for (int j = 0; j < 4; j++) {
        int qrow = qw + g * 4 + j;
        int mv = mrow[(long)qrow * S_ + key];
        float sc = s[j] * 0.125f + (mv ? 0.f : -1e9f);
        float pv = __expf(sc) * lsum[j];
        attn[((long)bh * S_ + qrow) * S_ + key] = pv;
        pbase[(g * 4 + j) * 136 + nb * 16 + li] = f2b(pv);
      }
    }
    __syncthreads();
#pragma unroll
    for (int kc = 0; kc < 4; kc++) {
      short8 ap = *(const short8*)(&pbase[li * 136 + kc * 32 + g * 8]);
#pragma unroll
      for (int nb2 = 0; nb2 < 4; nb2++) {
        short8 bv = *(const short8*)(&vt_lds[(nb2 * 16 + li) * 136 + kc * 32 + g * 8]);
        c[nb2] = __builtin_amdgcn_mfma_f32_16x16x32_bf16(ap, bv, c[nb2], 0, 0, 0);
      }
    }
    __syncthreads();
  }

#pragma unroll
  for (int nb2 = 0; nb2 < 4; nb2++) {
#pragma unroll
    for (int j = 0; j < 4; j++) {
      int qrow = qw + g * 4 + j;
      ctx[((long)(b * S_ + qrow)) * D_ + h * 64 + nb2 * 16 + li] = f2b(c[nb2][j]);
    }
  }
}

extern "C" void kernel_launch(void* const* d_in, const int* in_sizes, int n_in,
                              void* d_out, int out_size, void* d_ws, size_t ws_size,
                              hipStream_t stream) {
  const float* Q = (const float*)d_in[0];
  const float* K = (const float*)d_in[1];
  const float* V = (const float*)d_in[2];
  const int* mask = (const int*)d_in[3];
  const float* Wq = (const float*)d_in[4];
  const float* bq = (const float*)d_in[5];
  const float* Wk = (const float*)d_in[6];
  const float* bk = (const float*)d_in[7];
  const float* Wv = (const float*)d_in[8];
  const float* bv = (const float*)d_in[9];
  const float* Wo = (const float*)d_in[10];
  const float* bo = (const float*)d_in[11];

  float* out = (float*)d_out;           // (B,S,D) f32
  float* attn = out + TSZ;              // (B,H,S,S) f32

  unsigned short* ws = (unsigned short*)d_ws;
  unsigned short* q = ws;
  unsigned short* kk = ws + TSZ;
  unsigned short* v = ws + 2 * TSZ;
  unsigned short* vt = ws + 3 * TSZ;
  unsigned short* ctx = ws + 4 * TSZ;

  dim3 gg(64, 8), bb(256);
  gemm_kernel<false, 1><<<gg, bb, 0, stream>>>(Q, Wq, bq, q, 8192, 1024, 1024);
  gemm_kernel<false, 1><<<gg, bb, 0, stream>>>(K, Wk, bk, kk, 8192, 1024, 1024);
  gemm_kernel<false, 1><<<gg, bb, 0, stream>>>(V, Wv, bv, v, 8192, 1024, 1024);
  transpose_v<<<dim3(32, 64), bb, 0, stream>>>(v, vt);
  attn_kernel<<<dim3(32, 64), bb, 0, stream>>>(q, kk, vt, mask, attn, ctx);
  gemm_kernel<true, 0><<<gg, bb, 0, stream>>>(ctx, Wo, bo, out, 8192, 1024, 1024);
}

// Round 3
// 706.599 us; speedup vs baseline: 1.7729x; 1.7729x over previous
//
#include <hip/hip_runtime.h>
#include <hip/hip_bf16.h>

#define B_ 4
#define S_ 2048
#define D_ 1024
#define H_ 16
#define TSZ 8388608L  // B*S*D elements

typedef short short8 __attribute__((ext_vector_type(8)));
typedef float f32x4 __attribute__((ext_vector_type(4)));

__device__ inline unsigned short f2b(float f) {
  __hip_bfloat16 h = __float2bfloat16(f);
  return __builtin_bit_cast(unsigned short, h);
}
__device__ inline int i4c(const int4& v, int r) {
  return r == 0 ? v.x : r == 1 ? v.y : r == 2 ? v.z : v.w;
}

// ---------------- weight transpose: W f32 [K][N] -> Wt bf16 [N][K] ---------
__global__ __launch_bounds__(256) void transpose_w(
    const float* __restrict__ W, unsigned short* __restrict__ Wt) {
  __shared__ unsigned short t[64 * 72];  // [k][n] pitch 72
  const int tid = threadIdx.x;
  const int k0 = blockIdx.x * 64, n0 = blockIdx.y * 64;
#pragma unroll
  for (int p = 0; p < 4; p++) {
    int e = (p * 256 + tid) * 4;
    int r = e >> 6, c = e & 63;
    float4 v = *(const float4*)(W + (long)(k0 + r) * D_ + n0 + c);
    ushort4 u;
    u.x = f2b(v.x); u.y = f2b(v.y); u.z = f2b(v.z); u.w = f2b(v.w);
    *(ushort4*)(&t[r * 72 + c]) = u;
  }
  __syncthreads();
#pragma unroll
  for (int p = 0; p < 2; p++) {
    int e = (p * 256 + tid) * 8;
    int n = e >> 6, kc = e & 63;
    short8 x;
#pragma unroll
    for (int i = 0; i < 8; i++) x[i] = (short)t[(kc + i) * 72 + n];
    *(short8*)(Wt + (long)(n0 + n) * D_ + k0 + kc) = x;
  }
}

// ---------------- GEMM: C[M,N] = A[M,K] @ Wt^T + bias ----------------------
// Wt is bf16 [N][K]. MODE 0: out f32 [row][col]
// MODE 1: out bf16 head-major (b,h,s,dd): [((b*H+h)*S+s)*64+dd]
// MODE 2: out bf16 head-transposed (b,h,dd,s): [((b*H+h)*64+dd)*S+s]
template <bool ABF16, int MODE>
__global__ __launch_bounds__(256) void gemm_kernel(
    const void* __restrict__ Av, const unsigned short* __restrict__ Wt,
    const float* __restrict__ bias, void* __restrict__ outv,
    int M, int N, int K) {
  __shared__ unsigned short Asm[128 * 40];   // [row][k] pitch 40
  __shared__ unsigned short Bsm[128 * 40];   // [n][k] pitch 40
  const int tid = threadIdx.x;
  const int lane = tid & 63, wid = tid >> 6;
  const int g = lane >> 4, li = lane & 15;
  const int wm = wid >> 1, wn = wid & 1;
  const long bm = (long)blockIdx.x * 128;
  const long bn = (long)blockIdx.y * 128;

  f32x4 acc[4][4];
#pragma unroll
  for (int i = 0; i < 4; i++)
#pragma unroll
    for (int j = 0; j < 4; j++) acc[i][j] = (f32x4){0.f, 0.f, 0.f, 0.f};

  for (int kt = 0; kt < K / 32; ++kt) {
    const int k0 = kt * 32;
    if (ABF16) {
      const unsigned short* A = (const unsigned short*)Av;
#pragma unroll
      for (int p = 0; p < 2; p++) {
        int e = (p * 256 + tid) * 8;
        int r = e >> 5, c = e & 31;
        *(short8*)(&Asm[r * 40 + c]) = *(const short8*)(A + (bm + r) * K + k0 + c);
      }
    } else {
      const float* A = (const float*)Av;
#pragma unroll
      for (int p = 0; p < 4; p++) {
        int e = (p * 256 + tid) * 4;
        int r = e >> 5, c = e & 31;
        float4 v = *(const float4*)(A + (bm + r) * K + k0 + c);
        ushort4 u;
        u.x = f2b(v.x); u.y = f2b(v.y); u.z = f2b(v.z); u.w = f2b(v.w);
        *(ushort4*)(&Asm[r * 40 + c]) = u;
      }
    }
#pragma unroll
    for (int p = 0; p < 2; p++) {
      int e = (p * 256 + tid) * 8;
      int n = e >> 5, c = e & 31;
      *(short8*)(&Bsm[n * 40 + c]) = *(const short8*)(Wt + (bn + n) * K + k0 + c);
    }
    __syncthreads();
    short8 af[4], bf[4];
#pragma unroll
    for (int i = 0; i < 4; i++)
      af[i] = *(const short8*)(&Asm[(wm * 64 + i * 16 + li) * 40 + g * 8]);
#pragma unroll
    for (int i = 0; i < 4; i++)
      bf[i] = *(const short8*)(&Bsm[(wn * 64 + i * 16 + li) * 40 + g * 8]);
#pragma unroll
    for (int i = 0; i < 4; i++)
#pragma unroll
      for (int j = 0; j < 4; j++)
        acc[i][j] =
            __builtin_amdgcn_mfma_f32_16x16x32_bf16(af[i], bf[j], acc[i][j], 0, 0, 0);
    __syncthreads();
  }

#pragma unroll
  for (int i = 0; i < 4; i++) {
    int row0 = (int)bm + wm * 64 + i * 16 + g * 4;
#pragma unroll
    for (int j = 0; j < 4; j++) {
      int col = (int)bn + wn * 64 + j * 16 + li;
      float bvv = bias[col];
      if (MODE == 2) {
        int b = row0 >> 11, s0 = row0 & 2047;
        int h = col >> 6, dd = col & 63;
        ushort4 u;
#pragma unroll
        for (int jj = 0; jj < 4; jj++) u[jj] = f2b(acc[i][j][jj] + bvv);
        *(ushort4*)((unsigned short*)outv +
                    ((long)(b * H_ + h) * 64 + dd) * S_ + s0) = u;
      } else {
#pragma unroll
        for (int jj = 0; jj < 4; jj++) {
          int row = row0 + jj;
          float v = acc[i][j][jj] + bvv;
          if (MODE == 0) {
            ((float*)outv)[(long)row * N + col] = v;
          } else {
            int b = row >> 11, s = row & 2047;
            int h = col >> 6, dd = col & 63;
            ((unsigned short*)outv)[(((long)(b * H_ + h)) * S_ + s) * 64 + dd] =
                f2b(v);
          }
        }
      }
    }
  }
}

// ---------------- fused scores/softmax/PV (swapped QK^T) -------------------
__global__ __launch_bounds__(256) void attn_kernel(
    const unsigned short* __restrict__ q,   // (BH,S,64)
    const unsigned short* __restrict__ k,   // (BH,S,64)
    const unsigned short* __restrict__ vt,  // (BH,64,S)
    const int* __restrict__ mask,           // (B,S,S)
    float* __restrict__ attn,               // (BH,S,S) f32
    unsigned short* __restrict__ ctx) {     // (B,S,D) bf16
  __shared__ unsigned short k_lds[128 * 72];      // [key][dd] pitch 72
  __shared__ unsigned short vt_lds[64 * 136];     // [dd][key] pitch 136
  __shared__ unsigned short p_lds[4 * 16 * 136];  // per-wave [qrow][key]
  const int tid = threadIdx.x;
  const int lane = tid & 63, wid = tid >> 6;
  const int g = lane >> 4, li = lane & 15;
  const int bh = blockIdx.y;
  const int b = bh >> 4, h = bh & 15;
  const int qw = blockIdx.x * 64 + wid * 16;
  const int qs = qw + li;  // per-lane score row

  const unsigned short* qp = q + ((long)bh * S_ + qw) * 64;
  const short8 aq0 = *(const short8*)(qp + li * 64 + g * 8);
  const short8 aq1 = *(const short8*)(qp + li * 64 + 32 + g * 8);
  const int* mrow = mask + (long)b * S_ * S_ + (long)qs * S_;  // per-lane

  const unsigned short* kbase = k + (long)bh * S_ * 64;
  const unsigned short* vbase = vt + (long)bh * 64 * S_;
  // staging index helpers (per-thread, fixed)
  int kr[4], kc_[4], vr[4], vc[4];
#pragma unroll
  for (int p = 0; p < 4; p++) {
    int e = (p * 256 + tid) * 8;
    kr[p] = e >> 6; kc_[p] = e & 63;   // K tile 128x64
    vr[p] = e >> 7; vc[p] = e & 127;   // V tile 64x128
  }

  // ---- pass 1: denominators ----
  float lsum = 0.f;
  short8 kreg[4];
#pragma unroll
  for (int p = 0; p < 4; p++)
    kreg[p] = *(const short8*)(kbase + (long)kr[p] * 64 + kc_[p]);
  for (int kt = 0; kt < 16; ++kt) {
    __syncthreads();
#pragma unroll
    for (int p = 0; p < 4; p++)
      *(short8*)(&k_lds[kr[p] * 72 + kc_[p]]) = kreg[p];
    if (kt < 15) {
#pragma unroll
      for (int p = 0; p < 4; p++)
        kreg[p] = *(const short8*)(kbase + ((long)(kt + 1) * 128 + kr[p]) * 64 + kc_[p]);
    }
    int4 m4[8];
    const int4* mp = (const int4*)(mrow + kt * 128);
#pragma unroll
    for (int nb = 0; nb < 8; nb++) m4[nb] = mp[nb * 4 + g];
    __syncthreads();
#pragma unroll
    for (int nb = 0; nb < 8; nb++) {
      short8 b0 = *(const short8*)(&k_lds[(nb * 16 + li) * 72 + g * 8]);
      short8 b1 = *(const short8*)(&k_lds[(nb * 16 + li) * 72 + 32 + g * 8]);
      f32x4 s = (f32x4){0.f, 0.f, 0.f, 0.f};
      s = __builtin_amdgcn_mfma_f32_16x16x32_bf16(b0, aq0, s, 0, 0, 0);
      s = __builtin_amdgcn_mfma_f32_16x16x32_bf16(b1, aq1, s, 0, 0, 0);
#pragma unroll
      for (int r = 0; r < 4; r++) {
        float sc = s[r] * 0.125f + (i4c(m4[nb], r) ? 0.f : -1e9f);
        lsum += __expf(sc);
      }
    }
  }
  lsum += __shfl_xor(lsum, 16);
  lsum += __shfl_xor(lsum, 32);
  const float linv = (lsum > 0.f) ? 1.0f / lsum : 0.f;

  // ---- pass 2: probs + PV ----
  f32x4 c[4];
#pragma unroll
  for (int i = 0; i < 4; i++) c[i] = (f32x4){0.f, 0.f, 0.f, 0.f};
  unsigned short* pbase = &p_lds[wid * 16 * 136];

  short8 vreg[4];
#pragma unroll
  for (int p = 0; p < 4; p++) {
    kreg[p] = *(const short8*)(kbase + (long)kr[p] * 64 + kc_[p]);
    vreg[p] = *(const short8*)(vbase + (long)vr[p] * S_ + vc[p]);
  }
  for (int kt = 0; kt < 16; ++kt) {
    __syncthreads();
#pragma unroll
    for (int p = 0; p < 4; p++) {
      *(short8*)(&k_lds[kr[p] * 72 + kc_[p]]) = kreg[p];
      *(short8*)(&vt_lds[vr[p] * 136 + vc[p]]) = vreg[p];
    }
    if (kt < 15) {
#pragma unroll
      for (int p = 0; p < 4; p++) {
        kreg[p] = *(const short8*)(kbase + ((long)(kt + 1) * 128 + kr[p]) * 64 + kc_[p]);
        vreg[p] = *(const short8*)(vbase + (long)vr[p] * S_ + (kt + 1) * 128 + vc[p]);
      }
    }
    int4 m4[8];
    const int4* mp = (const int4*)(mrow + kt * 128);
#pragma unroll
    for (int nb = 0; nb < 8; nb++) m4[nb] = mp[nb * 4 + g];
    __syncthreads();
    float* arow = attn + ((long)bh * S_ + qs) * S_ + kt * 128;
#pragma unroll
    for (int nb = 0; nb < 8; nb++) {
      short8 b0 = *(const short8*)(&k_lds[(nb * 16 + li) * 72 + g * 8]);
      short8 b1 = *(const short8*)(&k_lds[(nb * 16 + li) * 72 + 32 + g * 8]);
      f32x4 s = (f32x4){0.f, 0.f, 0.f, 0.f};
      s = __builtin_amdgcn_mfma_f32_16x16x32_bf16(b0, aq0, s, 0, 0, 0);
      s = __builtin_amdgcn_mfma_f32_16x16x32_bf16(b1, aq1, s, 0, 0, 0);
      f32x4 pf;
      ushort4 pu;
#pragma unroll
      for (int r = 0; r < 4; r++) {
        float sc = s[r] * 0.125f + (i4c(m4[nb], r) ? 0.f : -1e9f);
        float pv = __expf(sc) * linv;
        pf[r] = pv;
        pu[r] = f2b(pv);
      }
      *(f32x4*)(arow + nb * 16 + g * 4) = pf;
      *(ushort4*)(&pbase[li * 136 + nb * 16 + g * 4]) = pu;
    }
#pragma unroll
    for (int kc = 0; kc < 4; kc++) {
      short8 ap = *(const short8*)(&pbase[li * 136 + kc * 32 + g * 8]);
#pragma unroll
      for (int nb2 = 0; nb2 < 4; nb2++) {
        short8 bv = *(const short8*)(&vt_lds[(nb2 * 16 + li) * 136 + kc * 32 + g * 8]);
        c[nb2] = __builtin_amdgcn_mfma_f32_16x16x32_bf16(ap, bv, c[nb2], 0, 0, 0);
      }
    }
  }

#pragma unroll
  for (int nb2 = 0; nb2 < 4; nb2++) {
#pragma unroll
    for (int j = 0; j < 4; j++) {
      int qrow = qw + g * 4 + j;
      ctx[((long)(b * S_ + qrow)) * D_ + h * 64 + nb2 * 16 + li] = f2b(c[nb2][j]);
    }
  }
}

extern "C" void kernel_launch(void* const* d_in, const int* in_sizes, int n_in,
                              void* d_out, int out_size, void* d_ws, size_t ws_size,
                              hipStream_t stream) {
  const float* Q = (const float*)d_in[0];
  const float* K = (const float*)d_in[1];
  const float* V = (const float*)d_in[2];
  const int* mask = (const int*)d_in[3];
  const float* Wq = (const float*)d_in[4];
  const float* bq = (const float*)d_in[5];
  const float* Wk = (const float*)d_in[6];
  const float* bk = (const float*)d_in[7];
  const float* Wv = (const float*)d_in[8];
  const float* bv = (const float*)d_in[9];
  const float* Wo = (const float*)d_in[10];
  const float* bo = (const float*)d_in[11];

  float* out = (float*)d_out;  // (B,S,D) f32
  float* attn = out + TSZ;     // (B,H,S,S) f32

  unsigned short* ws = (unsigned short*)d_ws;
  unsigned short* qh = ws;                  // (BH,S,64)
  unsigned short* kh = ws + TSZ;            // (BH,S,64)
  unsigned short* vt = ws + 2 * TSZ;        // (BH,64,S)
  unsigned short* ctx = ws + 3 * TSZ;       // (B,S,D) bf16
  unsigned short* wtq = ws + 4 * TSZ;
  unsigned short* wtk = wtq + 1048576;
  unsigned short* wtv = wtk + 1048576;
  unsigned short* wto = wtv + 1048576;

  dim3 bb(256);
  transpose_w<<<dim3(16, 16), bb, 0, stream>>>(Wq, wtq);
  transpose_w<<<dim3(16, 16), bb, 0, stream>>>(Wk, wtk);
  transpose_w<<<dim3(16, 16), bb, 0, stream>>>(Wv, wtv);
  transpose_w<<<dim3(16, 16), bb, 0, stream>>>(Wo, wto);

  dim3 gg(64, 8);
  gemm_kernel<false, 1><<<gg, bb, 0, stream>>>(Q, wtq, bq, qh, 8192, 1024, 1024);
  gemm_kernel<false, 1><<<gg, bb, 0, stream>>>(K, wtk, bk, kh, 8192, 1024, 1024);
  gemm_kernel<false, 2><<<gg, bb, 0, stream>>>(V, wtv, bv, vt, 8192, 1024, 1024);
  attn_kernel<<<dim3(32, 64), bb, 0, stream>>>(qh, kh, vt, mask, attn, ctx);
  gemm_kernel<true, 0><<<gg, bb, 0, stream>>>(ctx, wto, bo, out, 8192, 1024, 1024);
}

// Round 4
// 637.770 us; speedup vs baseline: 1.9642x; 1.1079x over previous
//
#include <hip/hip_runtime.h>
#include <hip/hip_bf16.h>

#define B_ 4
#define S_ 2048
#define D_ 1024
#define H_ 16
#define TSZ 8388608L  // B*S*D elements

typedef short short8 __attribute__((ext_vector_type(8)));
typedef float f32x4 __attribute__((ext_vector_type(4)));

__device__ inline unsigned short f2b(float f) {
  __hip_bfloat16 h = __float2bfloat16(f);
  return __builtin_bit_cast(unsigned short, h);
}
__device__ inline int i4c(const int4& v, int r) {
  return r == 0 ? v.x : r == 1 ? v.y : r == 2 ? v.z : v.w;
}
// async global->LDS, 16 bytes per lane; LDS dest must be wave-uniform base
__device__ inline void gld16(const unsigned short* g, unsigned short* l) {
  __builtin_amdgcn_global_load_lds(
      (const __attribute__((address_space(1))) void*)g,
      (__attribute__((address_space(3))) void*)l, 16, 0, 0);
}

// ---------------- f32 -> bf16 convert (contiguous) -------------------------
__global__ __launch_bounds__(256) void cvt_bf16(const float* __restrict__ in,
                                                unsigned short* __restrict__ out) {
  long i = ((long)blockIdx.x * 256 + threadIdx.x) * 8;
  float4 a = *(const float4*)(in + i);
  float4 b = *(const float4*)(in + i + 4);
  short8 u;
  u[0] = (short)f2b(a.x); u[1] = (short)f2b(a.y);
  u[2] = (short)f2b(a.z); u[3] = (short)f2b(a.w);
  u[4] = (short)f2b(b.x); u[5] = (short)f2b(b.y);
  u[6] = (short)f2b(b.z); u[7] = (short)f2b(b.w);
  *(short8*)(out + i) = u;
}

// ---------------- weight transpose: W f32 [K][N] -> Wt bf16 [N][K] ---------
__global__ __launch_bounds__(256) void transpose_w(
    const float* __restrict__ W, unsigned short* __restrict__ Wt) {
  __shared__ unsigned short t[64 * 72];  // [k][n] pitch 72
  const int tid = threadIdx.x;
  const int k0 = blockIdx.x * 64, n0 = blockIdx.y * 64;
#pragma unroll
  for (int p = 0; p < 4; p++) {
    int e = (p * 256 + tid) * 4;
    int r = e >> 6, c = e & 63;
    float4 v = *(const float4*)(W + (long)(k0 + r) * D_ + n0 + c);
    ushort4 u;
    u.x = f2b(v.x); u.y = f2b(v.y); u.z = f2b(v.z); u.w = f2b(v.w);
    *(ushort4*)(&t[r * 72 + c]) = u;
  }
  __syncthreads();
#pragma unroll
  for (int p = 0; p < 2; p++) {
    int e = (p * 256 + tid) * 8;
    int n = e >> 6, kc = e & 63;
    short8 x;
#pragma unroll
    for (int i = 0; i < 8; i++) x[i] = (short)t[(kc + i) * 72 + n];
    *(short8*)(Wt + (long)(n0 + n) * D_ + k0 + kc) = x;
  }
}

// ---------------- GEMM: C[M,N] = A[M,K] @ Wt^T + bias (A bf16) -------------
// m97 structure: global_load_lds(16B) staging, linear LDS, 2-barrier K-loop.
// MODE 0: out f32 [row][col]
// MODE 1: out bf16 head-major (b,h,s,dd): [((b*H+h)*S+s)*64+dd]
// MODE 2: out bf16 head-transposed (b,h,dd,s): [((b*H+h)*64+dd)*S+s]
template <int MODE>
__global__ __launch_bounds__(256) void gemm_kernel(
    const unsigned short* __restrict__ A, const unsigned short* __restrict__ Wt,
    const float* __restrict__ bias, void* __restrict__ outv,
    int M, int N, int K) {
  __shared__ unsigned short Asm[128 * 32];
  __shared__ unsigned short Bsm[128 * 32];
  const int tid = threadIdx.x;
  const int lane = tid & 63, wid = tid >> 6;
  const int g = lane >> 4, li = lane & 15;
  const int wm = wid >> 1, wn = wid & 1;
  const long bm = (long)blockIdx.x * 128;
  const long bn = (long)blockIdx.y * 128;

  f32x4 acc[4][4];
#pragma unroll
  for (int i = 0; i < 4; i++)
#pragma unroll
    for (int j = 0; j < 4; j++) acc[i][j] = (f32x4){0.f, 0.f, 0.f, 0.f};

  for (int kt = 0; kt < K / 32; ++kt) {
    const int k0 = kt * 32;
    __syncthreads();
#pragma unroll
    for (int p = 0; p < 2; p++) {
      int ci = p * 256 + wid * 64 + lane;       // 16B chunk index in tile
      int r = ci >> 2, c = (ci & 3) * 8;        // row, col (elements)
      gld16(A + (bm + r) * (long)K + k0 + c, &Asm[(p * 256 + wid * 64) * 8]);
      gld16(Wt + (bn + r) * (long)K + k0 + c, &Bsm[(p * 256 + wid * 64) * 8]);
    }
    __syncthreads();
    short8 af[4], bf[4];
#pragma unroll
    for (int i = 0; i < 4; i++)
      af[i] = *(const short8*)(&Asm[(wm * 64 + i * 16 + li) * 32 + g * 8]);
#pragma unroll
    for (int i = 0; i < 4; i++)
      bf[i] = *(const short8*)(&Bsm[(wn * 64 + i * 16 + li) * 32 + g * 8]);
#pragma unroll
    for (int i = 0; i < 4; i++)
#pragma unroll
      for (int j = 0; j < 4; j++)
        acc[i][j] =
            __builtin_amdgcn_mfma_f32_16x16x32_bf16(af[i], bf[j], acc[i][j], 0, 0, 0);
  }

#pragma unroll
  for (int i = 0; i < 4; i++) {
    int row0 = (int)bm + wm * 64 + i * 16 + g * 4;
#pragma unroll
    for (int j = 0; j < 4; j++) {
      int col = (int)bn + wn * 64 + j * 16 + li;
      float bvv = bias[col];
      if (MODE == 2) {
        int b = row0 >> 11, s0 = row0 & 2047;
        int h = col >> 6, dd = col & 63;
        ushort4 u;
#pragma unroll
        for (int jj = 0; jj < 4; jj++) u[jj] = f2b(acc[i][j][jj] + bvv);
        *(ushort4*)((unsigned short*)outv +
                    ((long)(b * H_ + h) * 64 + dd) * S_ + s0) = u;
      } else {
#pragma unroll
        for (int jj = 0; jj < 4; jj++) {
          int row = row0 + jj;
          float v = acc[i][j][jj] + bvv;
          if (MODE == 0) {
            ((float*)outv)[(long)row * N + col] = v;
          } else {
            int b = row >> 11, s = row & 2047;
            int h = col >> 6, dd = col & 63;
            ((unsigned short*)outv)[(((long)(b * H_ + h)) * S_ + s) * 64 + dd] =
                f2b(v);
          }
        }
      }
    }
  }
}

// ---------------- fused scores/softmax/PV (swapped QK^T) -------------------
__global__ __launch_bounds__(256) void attn_kernel(
    const unsigned short* __restrict__ q,   // (BH,S,64)
    const unsigned short* __restrict__ k,   // (BH,S,64)
    const unsigned short* __restrict__ vt,  // (BH,64,S)
    const int* __restrict__ mask,           // (B,S,S)
    float* __restrict__ attn,               // (BH,S,S) f32
    unsigned short* __restrict__ ctx) {     // (B,S,D) bf16
  __shared__ unsigned short k_lds[128 * 72];      // [key][dd] pitch 72
  __shared__ unsigned short vt_lds[64 * 136];     // [dd][key] pitch 136
  __shared__ unsigned short p_lds[4 * 16 * 136];  // per-wave [qrow][key]
  const int tid = threadIdx.x;
  const int lane = tid & 63, wid = tid >> 6;
  const int g = lane >> 4, li = lane & 15;
  const int bh = blockIdx.y;
  const int b = bh >> 4, h = bh & 15;
  const int qw = blockIdx.x * 64 + wid * 16;
  const int qs = qw + li;  // per-lane score row

  const unsigned short* qp = q + ((long)bh * S_ + qw) * 64;
  const short8 aq0 = *(const short8*)(qp + li * 64 + g * 8);
  const short8 aq1 = *(const short8*)(qp + li * 64 + 32 + g * 8);
  const int* mrow = mask + (long)b * S_ * S_ + (long)qs * S_;  // per-lane

  const unsigned short* kbase = k + (long)bh * S_ * 64;
  const unsigned short* vbase = vt + (long)bh * 64 * S_;
  int kr[4], kc_[4], vr[4], vc[4];
#pragma unroll
  for (int p = 0; p < 4; p++) {
    int e = (p * 256 + tid) * 8;
    kr[p] = e >> 6; kc_[p] = e & 63;   // K tile 128x64
    vr[p] = e >> 7; vc[p] = e & 127;   // V tile 64x128
  }

  // ---- pass 1: denominators ----
  float lsum = 0.f;
  short8 kreg[4];
#pragma unroll
  for (int p = 0; p < 4; p++)
    kreg[p] = *(const short8*)(kbase + (long)kr[p] * 64 + kc_[p]);
  for (int kt = 0; kt < 16; ++kt) {
    __syncthreads();
#pragma unroll
    for (int p = 0; p < 4; p++)
      *(short8*)(&k_lds[kr[p] * 72 + kc_[p]]) = kreg[p];
    if (kt < 15) {
#pragma unroll
      for (int p = 0; p < 4; p++)
        kreg[p] = *(const short8*)(kbase + ((long)(kt + 1) * 128 + kr[p]) * 64 + kc_[p]);
    }
    int4 m4[8];
    const int4* mp = (const int4*)(mrow + kt * 128);
#pragma unroll
    for (int nb = 0; nb < 8; nb++) m4[nb] = mp[nb * 4 + g];
    __syncthreads();
#pragma unroll
    for (int nb = 0; nb < 8; nb++) {
      short8 b0 = *(const short8*)(&k_lds[(nb * 16 + li) * 72 + g * 8]);
      short8 b1 = *(const short8*)(&k_lds[(nb * 16 + li) * 72 + 32 + g * 8]);
      f32x4 s = (f32x4){0.f, 0.f, 0.f, 0.f};
      __builtin_amdgcn_s_setprio(1);
      s = __builtin_amdgcn_mfma_f32_16x16x32_bf16(b0, aq0, s, 0, 0, 0);
      s = __builtin_amdgcn_mfma_f32_16x16x32_bf16(b1, aq1, s, 0, 0, 0);
      __builtin_amdgcn_s_setprio(0);
#pragma unroll
      for (int r = 0; r < 4; r++) {
        float sc = s[r] * 0.125f + (i4c(m4[nb], r) ? 0.f : -1e9f);
        lsum += __expf(sc);
      }
    }
  }
  lsum += __shfl_xor(lsum, 16);
  lsum += __shfl_xor(lsum, 32);
  const float linv = (lsum > 0.f) ? 1.0f / lsum : 0.f;

  // ---- pass 2: probs + PV ----
  f32x4 c[4];
#pragma unroll
  for (int i = 0; i < 4; i++) c[i] = (f32x4){0.f, 0.f, 0.f, 0.f};
  unsigned short* pbase = &p_lds[wid * 16 * 136];

  short8 vreg[4];
#pragma unroll
  for (int p = 0; p < 4; p++) {
    kreg[p] = *(const short8*)(kbase + (long)kr[p] * 64 + kc_[p]);
    vreg[p] = *(const short8*)(vbase + (long)vr[p] * S_ + vc[p]);
  }
  for (int kt = 0; kt < 16; ++kt) {
    __syncthreads();
#pragma unroll
    for (int p = 0; p < 4; p++) {
      *(short8*)(&k_lds[kr[p] * 72 + kc_[p]]) = kreg[p];
      *(short8*)(&vt_lds[vr[p] * 136 + vc[p]]) = vreg[p];
    }
    if (kt < 15) {
#pragma unroll
      for (int p = 0; p < 4; p++) {
        kreg[p] = *(const short8*)(kbase + ((long)(kt + 1) * 128 + kr[p]) * 64 + kc_[p]);
        vreg[p] = *(const short8*)(vbase + (long)vr[p] * S_ + (kt + 1) * 128 + vc[p]);
      }
    }
    int4 m4[8];
    const int4* mp = (const int4*)(mrow + kt * 128);
#pragma unroll
    for (int nb = 0; nb < 8; nb++) m4[nb] = mp[nb * 4 + g];
    __syncthreads();
    float* arow = attn + ((long)bh * S_ + qs) * S_ + kt * 128;
#pragma unroll
    for (int nb = 0; nb < 8; nb++) {
      short8 b0 = *(const short8*)(&k_lds[(nb * 16 + li) * 72 + g * 8]);
      short8 b1 = *(const short8*)(&k_lds[(nb * 16 + li) * 72 + 32 + g * 8]);
      f32x4 s = (f32x4){0.f, 0.f, 0.f, 0.f};
      __builtin_amdgcn_s_setprio(1);
      s = __builtin_amdgcn_mfma_f32_16x16x32_bf16(b0, aq0, s, 0, 0, 0);
      s = __builtin_amdgcn_mfma_f32_16x16x32_bf16(b1, aq1, s, 0, 0, 0);
      __builtin_amdgcn_s_setprio(0);
      f32x4 pf;
      ushort4 pu;
#pragma unroll
      for (int r = 0; r < 4; r++) {
        float sc = s[r] * 0.125f + (i4c(m4[nb], r) ? 0.f : -1e9f);
        float pv = __expf(sc) * linv;
        pf[r] = pv;
        pu[r] = f2b(pv);
      }
      __builtin_nontemporal_store(pf, (f32x4*)(arow + nb * 16 + g * 4));
      *(ushort4*)(&pbase[li * 136 + nb * 16 + g * 4]) = pu;
    }
    __builtin_amdgcn_s_setprio(1);
#pragma unroll
    for (int kc = 0; kc < 4; kc++) {
      short8 ap = *(const short8*)(&pbase[li * 136 + kc * 32 + g * 8]);
#pragma unroll
      for (int nb2 = 0; nb2 < 4; nb2++) {
        short8 bv = *(const short8*)(&vt_lds[(nb2 * 16 + li) * 136 + kc * 32 + g * 8]);
        c[nb2] = __builtin_amdgcn_mfma_f32_16x16x32_bf16(ap, bv, c[nb2], 0, 0, 0);
      }
    }
    __builtin_amdgcn_s_setprio(0);
  }

#pragma unroll
  for (int nb2 = 0; nb2 < 4; nb2++) {
#pragma unroll
    for (int j = 0; j < 4; j++) {
      int qrow = qw + g * 4 + j;
      ctx[((long)(b * S_ + qrow)) * D_ + h * 64 + nb2 * 16 + li] = f2b(c[nb2][j]);
    }
  }
}

extern "C" void kernel_launch(void* const* d_in, const int* in_sizes, int n_in,
                              void* d_out, int out_size, void* d_ws, size_t ws_size,
                              hipStream_t stream) {
  const float* Q = (const float*)d_in[0];
  const float* K = (const float*)d_in[1];
  const float* V = (const float*)d_in[2];
  const int* mask = (const int*)d_in[3];
  const float* Wq = (const float*)d_in[4];
  const float* bq = (const float*)d_in[5];
  const float* Wk = (const float*)d_in[6];
  const float* bk = (const float*)d_in[7];
  const float* Wv = (const float*)d_in[8];
  const float* bv = (const float*)d_in[9];
  const float* Wo = (const float*)d_in[10];
  const float* bo = (const float*)d_in[11];

  float* out = (float*)d_out;  // (B,S,D) f32
  float* attn = out + TSZ;     // (B,H,S,S) f32

  unsigned short* ws = (unsigned short*)d_ws;
  unsigned short* qh = ws;              // (BH,S,64) bf16
  unsigned short* kh = ws + TSZ;        // (BH,S,64)
  unsigned short* vt = ws + 2 * TSZ;    // (BH,64,S)
  unsigned short* ctx = ws + 3 * TSZ;   // (B,S,D) bf16
  unsigned short* qbf = ws + 4 * TSZ;   // (B,S,D) bf16 inputs
  unsigned short* kbf = ws + 5 * TSZ;
  unsigned short* vbf = ws + 6 * TSZ;
  unsigned short* wtq = ws + 7 * TSZ;
  unsigned short* wtk = wtq + 1048576;
  unsigned short* wtv = wtk + 1048576;
  unsigned short* wto = wtv + 1048576;

  dim3 bb(256);
  cvt_bf16<<<4096, bb, 0, stream>>>(Q, qbf);
  cvt_bf16<<<4096, bb, 0, stream>>>(K, kbf);
  cvt_bf16<<<4096, bb, 0, stream>>>(V, vbf);
  transpose_w<<<dim3(16, 16), bb, 0, stream>>>(Wq, wtq);
  transpose_w<<<dim3(16, 16), bb, 0, stream>>>(Wk, wtk);
  transpose_w<<<dim3(16, 16), bb, 0, stream>>>(Wv, wtv);
  transpose_w<<<dim3(16, 16), bb, 0, stream>>>(Wo, wto);

  dim3 gg(64, 8);
  gemm_kernel<1><<<gg, bb, 0, stream>>>(qbf, wtq, bq, qh, 8192, 1024, 1024);
  gemm_kernel<1><<<gg, bb, 0, stream>>>(kbf, wtk, bk, kh, 8192, 1024, 1024);
  gemm_kernel<2><<<gg, bb, 0, stream>>>(vbf, wtv, bv, vt, 8192, 1024, 1024);
  attn_kernel<<<dim3(32, 64), bb, 0, stream>>>(qh, kh, vt, mask, attn, ctx);
  gemm_kernel<0><<<gg, bb, 0, stream>>>(ctx, wto, bo, out, 8192, 1024, 1024);
}

// Round 5
// 559.670 us; speedup vs baseline: 2.2383x; 1.1395x over previous
//
#include <hip/hip_runtime.h>
#include <hip/hip_bf16.h>

#define B_ 4
#define S_ 2048
#define D_ 1024
#define H_ 16
#define TSZ 8388608L  // B*S*D elements

typedef short short8 __attribute__((ext_vector_type(8)));
typedef float f32x4 __attribute__((ext_vector_type(4)));

__device__ inline unsigned short f2b(float f) {
  __hip_bfloat16 h = __float2bfloat16(f);
  return __builtin_bit_cast(unsigned short, h);
}
// async global->LDS, 16 bytes per lane; LDS dest must be wave-uniform base
__device__ inline void gld16(const unsigned short* g, unsigned short* l) {
  __builtin_amdgcn_global_load_lds(
      (const __attribute__((address_space(1))) void*)g,
      (__attribute__((address_space(3))) void*)l, 16, 0, 0);
}

// ---------------- mask pack: int32 (B,S,S) -> bitmask ----------------------
// word index = ((row*16 + kt)*4 + g), bit (nb*4+r) = mask[row][kt*128+nb*16+g*4+r]
__global__ __launch_bounds__(256) void mask_pack(const int* __restrict__ mask,
                                                 unsigned int* __restrict__ mp) {
  long t = (long)blockIdx.x * 256 + threadIdx.x;  // t = row*16 + kt
  const int4* p = (const int4*)(mask + (t >> 4) * (long)S_ + (t & 15) * 128);
  unsigned int w0 = 0, w1 = 0, w2 = 0, w3 = 0;
#pragma unroll
  for (int c = 0; c < 32; c++) {
    int4 v = p[c];
#pragma unroll
    for (int e = 0; e < 4; e++) {
      int k = c * 4 + e;
      int val = e == 0 ? v.x : e == 1 ? v.y : e == 2 ? v.z : v.w;
      int nb = k >> 4, p16 = k & 15;
      int gg = p16 >> 2, r = p16 & 3;
      unsigned bit = ((unsigned)val & 1u) << (nb * 4 + r);
      if (gg == 0) w0 |= bit; else if (gg == 1) w1 |= bit;
      else if (gg == 2) w2 |= bit; else w3 |= bit;
    }
  }
  *(uint4*)(mp + t * 4) = make_uint4(w0, w1, w2, w3);
}

// ---------------- f32 -> bf16 convert for Q,K,V (one launch) ---------------
__global__ __launch_bounds__(256) void cvt3(
    const float* __restrict__ Q, const float* __restrict__ K,
    const float* __restrict__ V, unsigned short* __restrict__ qo,
    unsigned short* __restrict__ ko, unsigned short* __restrict__ vo) {
  int seg = blockIdx.x >> 12;
  long i = ((long)(blockIdx.x & 4095) * 256 + threadIdx.x) * 8;
  const float* in = seg == 0 ? Q : seg == 1 ? K : V;
  unsigned short* out = seg == 0 ? qo : seg == 1 ? ko : vo;
  float4 a = *(const float4*)(in + i);
  float4 b = *(const float4*)(in + i + 4);
  short8 u;
  u[0] = (short)f2b(a.x); u[1] = (short)f2b(a.y);
  u[2] = (short)f2b(a.z); u[3] = (short)f2b(a.w);
  u[4] = (short)f2b(b.x); u[5] = (short)f2b(b.y);
  u[6] = (short)f2b(b.z); u[7] = (short)f2b(b.w);
  *(short8*)(out + i) = u;
}

// ---------------- weight transpose: W f32 [K][N] -> Wt bf16 [N][K] ---------
__global__ __launch_bounds__(256) void transpose_w(
    const float* __restrict__ W, unsigned short* __restrict__ Wt) {
  __shared__ unsigned short t[64 * 72];  // [k][n] pitch 72
  const int tid = threadIdx.x;
  const int k0 = blockIdx.x * 64, n0 = blockIdx.y * 64;
#pragma unroll
  for (int p = 0; p < 4; p++) {
    int e = (p * 256 + tid) * 4;
    int r = e >> 6, c = e & 63;
    float4 v = *(const float4*)(W + (long)(k0 + r) * D_ + n0 + c);
    ushort4 u;
    u.x = f2b(v.x); u.y = f2b(v.y); u.z = f2b(v.z); u.w = f2b(v.w);
    *(ushort4*)(&t[r * 72 + c]) = u;
  }
  __syncthreads();
#pragma unroll
  for (int p = 0; p < 2; p++) {
    int e = (p * 256 + tid) * 8;
    int n = e >> 6, kc = e & 63;
    short8 x;
#pragma unroll
    for (int i = 0; i < 8; i++) x[i] = (short)t[(kc + i) * 72 + n];
    *(short8*)(Wt + (long)(n0 + n) * D_ + k0 + kc) = x;
  }
}

// ---------------- GEMM: C[M,N] = A[M,K] @ Wt^T + bias (A bf16) -------------
template <int MODE>
__global__ __launch_bounds__(256) void gemm_kernel(
    const unsigned short* __restrict__ A, const unsigned short* __restrict__ Wt,
    const float* __restrict__ bias, void* __restrict__ outv,
    int M, int N, int K) {
  __shared__ unsigned short Asm[128 * 32];
  __shared__ unsigned short Bsm[128 * 32];
  const int tid = threadIdx.x;
  const int lane = tid & 63, wid = tid >> 6;
  const int g = lane >> 4, li = lane & 15;
  const int wm = wid >> 1, wn = wid & 1;
  const long bm = (long)blockIdx.x * 128;
  const long bn = (long)blockIdx.y * 128;

  f32x4 acc[4][4];
#pragma unroll
  for (int i = 0; i < 4; i++)
#pragma unroll
    for (int j = 0; j < 4; j++) acc[i][j] = (f32x4){0.f, 0.f, 0.f, 0.f};

  for (int kt = 0; kt < K / 32; ++kt) {
    const int k0 = kt * 32;
    __syncthreads();
#pragma unroll
    for (int p = 0; p < 2; p++) {
      int ci = p * 256 + wid * 64 + lane;
      int r = ci >> 2, c = (ci & 3) * 8;
      gld16(A + (bm + r) * (long)K + k0 + c, &Asm[(p * 256 + wid * 64) * 8]);
      gld16(Wt + (bn + r) * (long)K + k0 + c, &Bsm[(p * 256 + wid * 64) * 8]);
    }
    __syncthreads();
    short8 af[4], bf[4];
#pragma unroll
    for (int i = 0; i < 4; i++)
      af[i] = *(const short8*)(&Asm[(wm * 64 + i * 16 + li) * 32 + g * 8]);
#pragma unroll
    for (int i = 0; i < 4; i++)
      bf[i] = *(const short8*)(&Bsm[(wn * 64 + i * 16 + li) * 32 + g * 8]);
#pragma unroll
    for (int i = 0; i < 4; i++)
#pragma unroll
      for (int j = 0; j < 4; j++)
        acc[i][j] =
            __builtin_amdgcn_mfma_f32_16x16x32_bf16(af[i], bf[j], acc[i][j], 0, 0, 0);
  }

#pragma unroll
  for (int i = 0; i < 4; i++) {
    int row0 = (int)bm + wm * 64 + i * 16 + g * 4;
#pragma unroll
    for (int j = 0; j < 4; j++) {
      int col = (int)bn + wn * 64 + j * 16 + li;
      float bvv = bias[col];
      if (MODE == 2) {
        int b = row0 >> 11, s0 = row0 & 2047;
        int h = col >> 6, dd = col & 63;
        ushort4 u;
#pragma unroll
        for (int jj = 0; jj < 4; jj++) u[jj] = f2b(acc[i][j][jj] + bvv);
        *(ushort4*)((unsigned short*)outv +
                    ((long)(b * H_ + h) * 64 + dd) * S_ + s0) = u;
      } else {
#pragma unroll
        for (int jj = 0; jj < 4; jj++) {
          int row = row0 + jj;
          float v = acc[i][j][jj] + bvv;
          if (MODE == 0) {
            ((float*)outv)[(long)row * N + col] = v;
          } else {
            int b = row >> 11, s = row & 2047;
            int h = col >> 6, dd = col & 63;
            ((unsigned short*)outv)[(((long)(b * H_ + h)) * S_ + s) * 64 + dd] =
                f2b(v);
          }
        }
      }
    }
  }
}

// ---------------- fused scores/softmax/PV (swapped QK^T, P-in-reg) ---------
__global__ __launch_bounds__(256, 4) void attn_kernel(
    const unsigned short* __restrict__ q,    // (BH,S,64)
    const unsigned short* __restrict__ k,    // (BH,S,64)
    const unsigned short* __restrict__ vt,   // (BH,64,S)
    const unsigned int* __restrict__ mpk,    // packed mask
    float* __restrict__ attn,                // (BH,S,S) f32
    unsigned short* __restrict__ ctx) {      // (B,S,D) bf16
  __shared__ unsigned short k_lds[128 * 72];   // [key][dd] pitch 72
  __shared__ unsigned short vt_lds[64 * 136];  // [dd][pi-key] pitch 136
  const int tid = threadIdx.x;
  const int lane = tid & 63, wid = tid >> 6;
  const int g = lane >> 4, li = lane & 15;
  const int bh = blockIdx.y;
  const int b = bh >> 4, h = bh & 15;
  const int qw = blockIdx.x * 64 + wid * 16;
  const int qs = qw + li;  // per-lane score row

  const unsigned short* qp = q + ((long)bh * S_ + qw) * 64;
  const short8 aq0 = *(const short8*)(qp + li * 64 + g * 8);
  const short8 aq1 = *(const short8*)(qp + li * 64 + 32 + g * 8);
  const unsigned int* mp = mpk + (((long)b * S_ + qs) * 16) * 4 + g;

  const unsigned short* kbase = k + (long)bh * S_ * 64;
  const unsigned short* vbase = vt + (long)bh * 64 * S_;
  // precomputed per-thread offsets
  int kst[4], kgo[4], vst[4], vgo[4];
#pragma unroll
  for (int p = 0; p < 4; p++) {
    int e = (p * 256 + tid) * 8;
    int krr = e >> 6, kcc = e & 63;    // K tile 128x64
    kst[p] = krr * 72 + kcc;
    kgo[p] = krr * 64 + kcc;
    int vrr = e >> 7, vcc = e & 127;   // V tile 64x128
    // pi-permuted store base within 32-key chunk
    int c0 = ((vcc >> 5) << 5) + ((vcc & 8) << 1) + ((vcc & 16) >> 2);
    vst[p] = vrr * 136 + c0;
    vgo[p] = vrr * S_ + vcc;
  }

  // ---- pass 1: denominators ----
  float lsum = 0.f;
  short8 kreg[4];
#pragma unroll
  for (int p = 0; p < 4; p++)
    kreg[p] = *(const short8*)(kbase + kgo[p]);
  unsigned int mb_n = mp[0];
  for (int kt = 0; kt < 16; ++kt) {
    __syncthreads();
#pragma unroll
    for (int p = 0; p < 4; p++)
      *(short8*)(&k_lds[kst[p]]) = kreg[p];
    unsigned int mb = mb_n;
    if (kt < 15) {
#pragma unroll
      for (int p = 0; p < 4; p++)
        kreg[p] = *(const short8*)(kbase + (kt + 1) * 8192 + kgo[p]);
      mb_n = mp[(kt + 1) * 4];
    }
    __syncthreads();
#pragma unroll
    for (int nb = 0; nb < 8; nb++) {
      short8 b0 = *(const short8*)(&k_lds[(nb * 16 + li) * 72 + g * 8]);
      short8 b1 = *(const short8*)(&k_lds[(nb * 16 + li) * 72 + 32 + g * 8]);
      f32x4 s = (f32x4){0.f, 0.f, 0.f, 0.f};
      __builtin_amdgcn_s_setprio(1);
      s = __builtin_amdgcn_mfma_f32_16x16x32_bf16(b0, aq0, s, 0, 0, 0);
      s = __builtin_amdgcn_mfma_f32_16x16x32_bf16(b1, aq1, s, 0, 0, 0);
      __builtin_amdgcn_s_setprio(0);
#pragma unroll
      for (int r = 0; r < 4; r++) {
        float sc = s[r] * 0.125f + (((mb >> (nb * 4 + r)) & 1u) ? 0.f : -1e9f);
        lsum += __expf(sc);
      }
    }
  }
  lsum += __shfl_xor(lsum, 16);
  lsum += __shfl_xor(lsum, 32);
  const float linv = (lsum > 0.f) ? 1.0f / lsum : 0.f;

  // ---- pass 2: probs + PV ----
  f32x4 c[4];
#pragma unroll
  for (int i = 0; i < 4; i++) c[i] = (f32x4){0.f, 0.f, 0.f, 0.f};

  short8 vreg[4];
#pragma unroll
  for (int p = 0; p < 4; p++) {
    kreg[p] = *(const short8*)(kbase + kgo[p]);
    vreg[p] = *(const short8*)(vbase + vgo[p]);
  }
  mb_n = mp[0];
  for (int kt = 0; kt < 16; ++kt) {
    __syncthreads();
#pragma unroll
    for (int p = 0; p < 4; p++) {
      *(short8*)(&k_lds[kst[p]]) = kreg[p];
      // pi-permuted V store: split short8 into two b64 halves
      ushort4* vh = (ushort4*)&vreg[p];
      *(ushort4*)(&vt_lds[vst[p]]) = vh[0];
      *(ushort4*)(&vt_lds[vst[p] + 8]) = vh[1];
    }
    unsigned int mb = mb_n;
    if (kt < 15) {
#pragma unroll
      for (int p = 0; p < 4; p++) {
        kreg[p] = *(const short8*)(kbase + (kt + 1) * 8192 + kgo[p]);
        vreg[p] = *(const short8*)(vbase + (kt + 1) * 128 + vgo[p]);
      }
      mb_n = mp[(kt + 1) * 4];
    }
    __syncthreads();
    float* arow = attn + ((long)bh * S_ + qs) * S_ + kt * 128;
    short8 pu2[4];  // per-lane P fragments, pi-key order
#pragma unroll
    for (int nb = 0; nb < 8; nb++) {
      short8 b0 = *(const short8*)(&k_lds[(nb * 16 + li) * 72 + g * 8]);
      short8 b1 = *(const short8*)(&k_lds[(nb * 16 + li) * 72 + 32 + g * 8]);
      f32x4 s = (f32x4){0.f, 0.f, 0.f, 0.f};
      __builtin_amdgcn_s_setprio(1);
      s = __builtin_amdgcn_mfma_f32_16x16x32_bf16(b0, aq0, s, 0, 0, 0);
      s = __builtin_amdgcn_mfma_f32_16x16x32_bf16(b1, aq1, s, 0, 0, 0);
      __builtin_amdgcn_s_setprio(0);
      f32x4 pf;
      ushort4 pu;
#pragma unroll
      for (int r = 0; r < 4; r++) {
        float sc = s[r] * 0.125f + (((mb >> (nb * 4 + r)) & 1u) ? 0.f : -1e9f);
        float pv = __expf(sc) * linv;
        pf[r] = pv;
        pu[r] = f2b(pv);
      }
      __builtin_nontemporal_store(pf, (f32x4*)(arow + nb * 16 + g * 4));
      ((ushort4*)&pu2[nb >> 1])[nb & 1] = pu;
    }
    __builtin_amdgcn_s_setprio(1);
#pragma unroll
    for (int kc = 0; kc < 4; kc++) {
      short8 ap = pu2[kc];
#pragma unroll
      for (int nb2 = 0; nb2 < 4; nb2++) {
        short8 bv =
            *(const short8*)(&vt_lds[(nb2 * 16 + li) * 136 + kc * 32 + g * 8]);
        c[nb2] = __builtin_amdgcn_mfma_f32_16x16x32_bf16(ap, bv, c[nb2], 0, 0, 0);
      }
    }
    __builtin_amdgcn_s_setprio(0);
  }

#pragma unroll
  for (int nb2 = 0; nb2 < 4; nb2++) {
#pragma unroll
    for (int j = 0; j < 4; j++) {
      int qrow = qw + g * 4 + j;
      ctx[((long)(b * S_ + qrow)) * D_ + h * 64 + nb2 * 16 + li] = f2b(c[nb2][j]);
    }
  }
}

extern "C" void kernel_launch(void* const* d_in, const int* in_sizes, int n_in,
                              void* d_out, int out_size, void* d_ws, size_t ws_size,
                              hipStream_t stream) {
  const float* Q = (const float*)d_in[0];
  const float* K = (const float*)d_in[1];
  const float* V = (const float*)d_in[2];
  const int* mask = (const int*)d_in[3];
  const float* Wq = (const float*)d_in[4];
  const float* bq = (const float*)d_in[5];
  const float* Wk = (const float*)d_in[6];
  const float* bk = (const float*)d_in[7];
  const float* Wv = (const float*)d_in[8];
  const float* bv = (const float*)d_in[9];
  const float* Wo = (const float*)d_in[10];
  const float* bo = (const float*)d_in[11];

  float* out = (float*)d_out;  // (B,S,D) f32
  float* attn = out + TSZ;     // (B,H,S,S) f32
  // packed mask (2 MB) lives in the out region; overwritten by final GEMM
  unsigned int* mpack = (unsigned int*)d_out;

  unsigned short* ws = (unsigned short*)d_ws;
  unsigned short* qh = ws;              // (BH,S,64) bf16
  unsigned short* kh = ws + TSZ;        // (BH,S,64)
  unsigned short* vt = ws + 2 * TSZ;    // (BH,64,S)
  unsigned short* ctx = ws + 3 * TSZ;   // (B,S,D) bf16
  unsigned short* qbf = ws + 4 * TSZ;   // bf16 inputs
  unsigned short* kbf = ws + 5 * TSZ;
  unsigned short* vbf = ws + 6 * TSZ;
  unsigned short* wtq = ws + 7 * TSZ;
  unsigned short* wtk = wtq + 1048576;
  unsigned short* wtv = wtk + 1048576;
  unsigned short* wto = wtv + 1048576;

  dim3 bb(256);
  mask_pack<<<512, bb, 0, stream>>>(mask, mpack);
  cvt3<<<12288, bb, 0, stream>>>(Q, K, V, qbf, kbf, vbf);
  transpose_w<<<dim3(16, 16), bb, 0, stream>>>(Wq, wtq);
  transpose_w<<<dim3(16, 16), bb, 0, stream>>>(Wk, wtk);
  transpose_w<<<dim3(16, 16), bb, 0, stream>>>(Wv, wtv);
  transpose_w<<<dim3(16, 16), bb, 0, stream>>>(Wo, wto);

  dim3 gg(64, 8);
  gemm_kernel<1><<<gg, bb, 0, stream>>>(qbf, wtq, bq, qh, 8192, 1024, 1024);
  gemm_kernel<1><<<gg, bb, 0, stream>>>(kbf, wtk, bk, kh, 8192, 1024, 1024);
  gemm_kernel<2><<<gg, bb, 0, stream>>>(vbf, wtv, bv, vt, 8192, 1024, 1024);
  attn_kernel<<<dim3(32, 64), bb, 0, stream>>>(qh, kh, vt, mpack, attn, ctx);
  gemm_kernel<0><<<gg, bb, 0, stream>>>(ctx, wto, bo, out, 8192, 1024, 1024);
}